// Round 7
// baseline (571.309 us; speedup 1.0000x reference)
//
#include <hip/hip_runtime.h>
#include <math.h>

// Problem constants
constexpr int Bc   = 8;
constexpr int Sc   = 1024;
constexpr int HIDc = 1024;
constexpr int NHc  = 16;
constexpr int DHc  = 64;
constexpr int Mc   = Bc * Sc;                 // 8192 rows for all GEMMs
constexpr int Kc2  = 1024;                    // K dim for all GEMMs
constexpr float SCALE    = 8.0f;              // ref divides by DH**-0.5 == *sqrt(64)
constexpr float EPS_TERM = 1024.0f * 1e-8f;   // S * ZERO in the renorm denominator

typedef short s16x8 __attribute__((ext_vector_type(8)));   // 8 bf16/fp16 (4 VGPRs)
typedef float f32x4 __attribute__((ext_vector_type(4)));

__device__ __forceinline__ ushort f2bf(float f) {          // RNE float->bf16 bits
  unsigned u = __float_as_uint(f);
  u += 0x7FFFu + ((u >> 16) & 1u);
  return (ushort)(u >> 16);
}
__device__ __forceinline__ float bf2f(ushort h) {
  return __uint_as_float(((unsigned)h) << 16);
}
__device__ __forceinline__ ushort f2h(float f) {           // RNE float->fp16 bits
  _Float16 h = (_Float16)f;
  return *(ushort*)&h;
}
__device__ __forceinline__ float h2f(ushort u) {
  _Float16 h = *(_Float16*)&u;
  return (float)h;
}
__device__ __forceinline__ unsigned pk2h(float a, float b) {  // pack 2 fp16
  return (unsigned)f2h(a) | ((unsigned)f2h(b) << 16);
}

// async global->LDS, 16B per lane; LDS dest = wave-uniform base + lane*16
__device__ __forceinline__ void gl_lds16(const ushort* g, ushort* l) {
  __builtin_amdgcn_global_load_lds(
      (const __attribute__((address_space(1))) void*)g,
      (__attribute__((address_space(3))) void*)l, 16, 0, 0);
}

// split 8 fp32 -> bf16 hi8 + lo8 (RNE)
__device__ __forceinline__ void split8(const float4 v0, const float4 v1,
                                       s16x8& hi, s16x8& lo) {
  const float f[8] = {v0.x, v0.y, v0.z, v0.w, v1.x, v1.y, v1.z, v1.w};
  ushort h[8], l[8];
#pragma unroll
  for (int i = 0; i < 8; i++) {
    h[i] = f2bf(f[i]);
    l[i] = f2bf(f[i] - bf2f(h[i]));
  }
#pragma unroll
  for (int i = 0; i < 8; i++) { hi[i] = (short)h[i]; lo[i] = (short)l[i]; }
}

// ---------------------------------------------------------------------------
// Weight conversions (one launch): seg 0=Wq(bf16 split) 1=Wk(bf16 split)
//                                  seg 2=Wv(bf16)       3=Wo(fp16)
// ---------------------------------------------------------------------------
__global__ __launch_bounds__(256) void cvt_weights(
    const float4* __restrict__ Wq, const float4* __restrict__ Wk,
    const float4* __restrict__ Wv, const float4* __restrict__ Wo,
    ushort4* __restrict__ Wqh, ushort4* __restrict__ Wql,
    ushort4* __restrict__ Wkh, ushort4* __restrict__ Wkl,
    ushort4* __restrict__ Wvh, ushort4* __restrict__ Woh, int n4w)
{
  const int bpseg = n4w / 256;                 // blocks per segment (1024)
  const int seg   = blockIdx.x / bpseg;
  const int li    = (blockIdx.x - seg * bpseg) * 256 + threadIdx.x;
  if (li >= n4w) return;
  if (seg == 0) {
    const float4 v = Wq[li];
    ushort4 h, l;
    h.x = f2bf(v.x); l.x = f2bf(v.x - bf2f(h.x));
    h.y = f2bf(v.y); l.y = f2bf(v.y - bf2f(h.y));
    h.z = f2bf(v.z); l.z = f2bf(v.z - bf2f(h.z));
    h.w = f2bf(v.w); l.w = f2bf(v.w - bf2f(h.w));
    Wqh[li] = h; Wql[li] = l;
  } else if (seg == 1) {
    const float4 v = Wk[li];
    ushort4 h, l;
    h.x = f2bf(v.x); l.x = f2bf(v.x - bf2f(h.x));
    h.y = f2bf(v.y); l.y = f2bf(v.y - bf2f(h.y));
    h.z = f2bf(v.z); l.z = f2bf(v.z - bf2f(h.z));
    h.w = f2bf(v.w); l.w = f2bf(v.w - bf2f(h.w));
    Wkh[li] = h; Wkl[li] = l;
  } else if (seg == 2) {
    const float4 v = Wv[li];
    ushort4 h;
    h.x = f2bf(v.x); h.y = f2bf(v.y); h.z = f2bf(v.z); h.w = f2bf(v.w);
    Wvh[li] = h;
  } else {
    const float4 v = Wo[li];
    ushort4 h;
    h.x = f2h(v.x); h.y = f2h(v.y); h.z = f2h(v.z); h.w = f2h(v.w);
    Woh[li] = h;
  }
}

// ---------------------------------------------------------------------------
// Fused QKV projection GEMM. 1D grid 1536, XCD-locality swizzle:
//   lin&7 -> XCD; each XCD gets a contiguous (z,y)-run with all 8 x-blocks,
//   so A row-tiles are fetched once per XCD and ~one z's weights stay L2-resident.
// z<2 (Q,K): bf16 hi/lo 3-term (near-fp32). z=2 (V): single bf16 pass.
// Epilogues: Q -> fp16 hi/lo [B,NH,S,DH]; K -> fp16 [B,NH,S,DH];
//            V -> fp16 transposed [B,NH,DH,S].
// ---------------------------------------------------------------------------
__global__ __launch_bounds__(256, 3) void qkv_gemm(
    const float* __restrict__ Qf, const float* __restrict__ Kf,
    const float* __restrict__ Vf,
    const ushort* __restrict__ Wqh, const ushort* __restrict__ Wql,
    const ushort* __restrict__ Wkh, const ushort* __restrict__ Wkl,
    const ushort* __restrict__ Wvh,
    const float* __restrict__ bq, const float* __restrict__ bk,
    const float* __restrict__ bv,
    ushort* __restrict__ qhi, ushort* __restrict__ qlo,
    ushort* __restrict__ kf,  ushort* __restrict__ vt)
{
  __shared__ ushort AhL[4096];
  __shared__ ushort BhL[4096];
  __shared__ ushort AlL[4096];
  __shared__ ushort BlL[4096];

  // XCD swizzle: xcd = lin&7 (round-robin dispatch heuristic)
  const int lin = blockIdx.x;                 // 0..1535
  const int wk  = (lin & 7) * 192 + (lin >> 3);
  const int z   = wk >> 9;                    // 0..2
  const int rem = wk & 511;
  const int m0  = (rem >> 3) * 128;
  const int n0  = (rem & 7) * 128;

  const bool split = (z < 2);
  const float*  Af = (z == 0) ? Qf : (z == 1) ? Kf : Vf;
  const ushort* Bh = (z == 0) ? Wqh : (z == 1) ? Wkh : Wvh;
  const ushort* Bl = (z == 0) ? Wql : Wkl;   // unused when z==2
  const float* bias = (z == 0) ? bq : (z == 1) ? bk : bv;

  const int t    = threadIdx.x;
  const int w    = t >> 6;
  const int ln   = t & 63;
  const int col  = ln & 15;
  const int quad = ln >> 4;
  const int wm   = w >> 1, wn = w & 1;

  f32x4 acc[4][4] = {};
  const int sA = w * 128;  // this wave's 128-chunk staging range

  for (int k0 = 0; k0 < Kc2; k0 += 32) {
    // A fp32 loads to VGPRs BEFORE the barrier (prefetch over prev tile's MFMA)
    float4 av[2][2];
#pragma unroll
    for (int j = 0; j < 2; j++) {
      const int s = sA + j * 64 + ln;
      const int r = s & 127, c = s >> 7;
      const float4* ga = (const float4*)(Af + (size_t)(m0 + r) * Kc2 + k0 + c * 8);
      av[j][0] = ga[0];
      av[j][1] = ga[1];
    }

    __syncthreads();  // previous tile consumed

    // B (weights) via async global->LDS
#pragma unroll
    for (int j = 0; j < 2; j++) {
      const int s = sA + j * 64 + ln;
      const int r = s & 127, c = s >> 7;
      const size_t goB = (size_t)(n0 + r) * Kc2 + k0 + c * 8;
      gl_lds16(Bh + goB, &BhL[(size_t)(sA + j * 64) * 8]);
      if (split) gl_lds16(Bl + goB, &BlL[(size_t)(sA + j * 64) * 8]);
    }
    // A: split in registers, write chunk-major
#pragma unroll
    for (int j = 0; j < 2; j++) {
      const int s = sA + j * 64 + ln;
      s16x8 hi, lo;
      split8(av[j][0], av[j][1], hi, lo);
      *(s16x8*)&AhL[(size_t)s * 8] = hi;
      if (split) *(s16x8*)&AlL[(size_t)s * 8] = lo;
    }
    __syncthreads();

    s16x8 a_h[4], b_h[4], a_l[4], b_l[4];
#pragma unroll
    for (int i = 0; i < 4; i++) {
      const int ai = (quad * 128 + wm * 64 + i * 16 + col) * 8;
      const int bi = (quad * 128 + wn * 64 + i * 16 + col) * 8;
      a_h[i] = *(const s16x8*)&AhL[ai];
      b_h[i] = *(const s16x8*)&BhL[bi];
      if (split) {
        a_l[i] = *(const s16x8*)&AlL[ai];
        b_l[i] = *(const s16x8*)&BlL[bi];
      }
    }
#pragma unroll
    for (int i = 0; i < 4; i++)
#pragma unroll
      for (int jj = 0; jj < 4; jj++) {
        acc[i][jj] = __builtin_amdgcn_mfma_f32_16x16x32_bf16(a_h[i], b_h[jj], acc[i][jj], 0, 0, 0);
        if (split) {
          acc[i][jj] = __builtin_amdgcn_mfma_f32_16x16x32_bf16(a_h[i], b_l[jj], acc[i][jj], 0, 0, 0);
          acc[i][jj] = __builtin_amdgcn_mfma_f32_16x16x32_bf16(a_l[i], b_h[jj], acc[i][jj], 0, 0, 0);
        }
      }
  }

  // epilogue: C/D frag mapping col=lane&15, row=quad*4+reg
  const int mb = m0 + wm * 64;
  const int nb = n0 + wn * 64;
#pragma unroll
  for (int i = 0; i < 4; i++)
#pragma unroll
    for (int jj = 0; jj < 4; jj++) {
      const int n  = nb + jj * 16 + col;
      const float bvv = bias[n];
#pragma unroll
      for (int r = 0; r < 4; r++) {
        const int m   = mb + i * 16 + quad * 4 + r;
        const float v = acc[i][jj][r] + bvv;
        const int b_ = m >> 10, s = m & (Sc - 1);
        const int h_ = n >> 6,  d = n & (DHc - 1);
        if (z == 0) {           // Q: fp16 hi/lo, head layout
          const size_t off = (((size_t)b_ * NHc + h_) * Sc + s) * DHc + d;
          const ushort hb = f2h(v);
          qhi[off] = hb;
          qlo[off] = f2h(v - h2f(hb));
        } else if (z == 1) {    // K: fp16 single, head layout
          const size_t off = (((size_t)b_ * NHc + h_) * Sc + s) * DHc + d;
          kf[off] = f2h(v);
        } else {                // V: fp16, transposed head layout
          const size_t off = (((size_t)b_ * NHc + h_) * DHc + d) * Sc + s;
          vt[off] = f2h(v);
        }
      }
    }
}

// ---------------------------------------------------------------------------
// Output GEMM (fp16 inputs, fp32 out), XCD-locality swizzle.
// ---------------------------------------------------------------------------
__global__ __launch_bounds__(256, 3) void o_gemm(
    const ushort* __restrict__ Ag, const ushort* __restrict__ Bg,
    const float* __restrict__ bias, float* __restrict__ C)
{
  __shared__ ushort AhL[4096];
  __shared__ ushort BhL[4096];

  const int lin = blockIdx.x;                 // 0..511
  const int wk  = (lin & 7) * 64 + (lin >> 3);
  const int m0  = (wk >> 3) * 128;
  const int n0  = (wk & 7) * 128;

  const int t    = threadIdx.x;
  const int w    = t >> 6;
  const int ln   = t & 63;
  const int col  = ln & 15;
  const int quad = ln >> 4;
  const int wm   = w >> 1, wn = w & 1;

  f32x4 acc[4][4] = {};
  const int sA = w * 128;

  for (int k0 = 0; k0 < Kc2; k0 += 32) {
    __syncthreads();
#pragma unroll
    for (int j = 0; j < 2; j++) {
      const int s = sA + j * 64 + ln;
      const int r = s & 127, c = s >> 7;
      gl_lds16(Ag + (size_t)(m0 + r) * Kc2 + k0 + c * 8, &AhL[(size_t)(sA + j * 64) * 8]);
      gl_lds16(Bg + (size_t)(n0 + r) * Kc2 + k0 + c * 8, &BhL[(size_t)(sA + j * 64) * 8]);
    }
    __syncthreads();

    s16x8 a_h[4], b_h[4];
#pragma unroll
    for (int i = 0; i < 4; i++) {
      a_h[i] = *(const s16x8*)&AhL[(quad * 128 + wm * 64 + i * 16 + col) * 8];
      b_h[i] = *(const s16x8*)&BhL[(quad * 128 + wn * 64 + i * 16 + col) * 8];
    }
#pragma unroll
    for (int i = 0; i < 4; i++)
#pragma unroll
      for (int jj = 0; jj < 4; jj++)
        acc[i][jj] = __builtin_amdgcn_mfma_f32_16x16x32_f16(a_h[i], b_h[jj], acc[i][jj], 0, 0, 0);
  }

  const int mb = m0 + wm * 64;
  const int nb = n0 + wn * 64;
#pragma unroll
  for (int i = 0; i < 4; i++)
#pragma unroll
    for (int jj = 0; jj < 4; jj++) {
      const int n  = nb + jj * 16 + col;
      const float bvv = bias[n];
#pragma unroll
      for (int r = 0; r < 4; r++) {
        const int m = mb + i * 16 + quad * 4 + r;
        C[(size_t)m * HIDc + n] = acc[i][jj][r] + bvv;
      }
    }
}

// ---------------------------------------------------------------------------
// MFMA flash attention, S^T orientation, fp16 (R7).
// k single fp16 + q fp16 hi/lo -> QK^T = 4 MFMA (was 6); P/V/ctx fp16.
// ---------------------------------------------------------------------------
constexpr int LDP = 72;   // P LDS row stride (ushorts)

__global__ __launch_bounds__(256, 6) void attn_mfma(
    const ushort* __restrict__ qhi, const ushort* __restrict__ qlo,
    const ushort* __restrict__ kf,  const ushort* __restrict__ vt,
    const float* __restrict__ Qm,   const float* __restrict__ Km,
    ushort* __restrict__ ctx)
{
  __shared__ ushort KfL[4096];      // chunk c*64+r = K[r][c*8..+8]
  __shared__ ushort VtL[4096];      // chunk c*64+d = V^T[d][c*8..+8]
  __shared__ ushort PmL[64 * LDP];
  __shared__ float  kmL[64];

  const int t    = threadIdx.x;
  const int w    = t >> 6;
  const int ln   = t & 63;
  const int col  = ln & 15;
  const int quad = ln >> 4;

  // XCD-aware remap: 16 whole heads per XCD, q-tiles of a head on one XCD.
  const int id  = blockIdx.x;          // 0..2047
  const int xcd = id & 7;
  const int j   = id >> 3;             // 0..255
  const int bh  = xcd * 16 + (j >> 4);
  const int qt  = j & 15;
  const int b   = bh >> 4;
  const int h   = bh & 15;

  const int qbase = qt * 64 + w * 16;
  const size_t headoff = (size_t)bh * Sc * DHc;

  s16x8 qh0, qh1, ql0, ql1;
  {
    const size_t ro = headoff + (size_t)(qbase + col) * DHc + quad * 8;
    qh0 = *(const s16x8*)(qhi + ro);
    qh1 = *(const s16x8*)(qhi + ro + 32);
    ql0 = *(const s16x8*)(qlo + ro);
    ql1 = *(const s16x8*)(qlo + ro + 32);
  }

  f32x4 OT[4] = {{0,0,0,0},{0,0,0,0},{0,0,0,0},{0,0,0,0}};
  float mrow = -INFINITY;
  float Zp = 0.0f, Zmp = 0.0f;

  for (int k0 = 0; k0 < Sc; k0 += 64) {
    __syncthreads();
#pragma unroll
    for (int jj = 0; jj < 2; jj++) {
      const int c = jj * 4 + w;
      const size_t gk = headoff + (size_t)(k0 + ln) * DHc + c * 8;
      const size_t gv = headoff + (size_t)ln * Sc + k0 + c * 8;
      gl_lds16(kf + gk, &KfL[c * 512]);
      gl_lds16(vt + gv, &VtL[c * 512]);
    }
    if (t < 64) kmL[t] = Km[b * Sc + k0 + t];
    __syncthreads();

    float s[4][4];
#pragma unroll
    for (int ks = 0; ks < 4; ks++) {
      const int base0 = (quad * 64 + ks * 16 + col) * 8;
      const int base1 = ((quad + 4) * 64 + ks * 16 + col) * 8;
      const s16x8 k0f = *(const s16x8*)&KfL[base0];
      const s16x8 k1f = *(const s16x8*)&KfL[base1];
      f32x4 a = {0,0,0,0};
      a = __builtin_amdgcn_mfma_f32_16x16x32_f16(k0f, qh0, a, 0, 0, 0);
      a = __builtin_amdgcn_mfma_f32_16x16x32_f16(k1f, qh1, a, 0, 0, 0);
      a = __builtin_amdgcn_mfma_f32_16x16x32_f16(k0f, ql0, a, 0, 0, 0);
      a = __builtin_amdgcn_mfma_f32_16x16x32_f16(k1f, ql1, a, 0, 0, 0);
#pragma unroll
      for (int r = 0; r < 4; r++) s[ks][r] = a[r] * SCALE;
    }

    float tmax = s[0][0];
#pragma unroll
    for (int ks = 0; ks < 4; ks++)
#pragma unroll
      for (int r = 0; r < 4; r++) tmax = fmaxf(tmax, s[ks][r]);
    tmax = fmaxf(tmax, __shfl_xor(tmax, 16, 64));
    tmax = fmaxf(tmax, __shfl_xor(tmax, 32, 64));

    const float mn    = fmaxf(mrow, tmax);
    const float alpha = __expf(mrow - mn);
    mrow = mn;

    float ps = 0.0f, pms = 0.0f;
    const int prow = (w * 16 + col) * LDP;
#pragma unroll
    for (int ks = 0; ks < 4; ks++) {
      const float4 km4 = *(const float4*)&kmL[ks * 16 + quad * 4];
      const float p0 = __expf(s[ks][0] - mn), p1 = __expf(s[ks][1] - mn);
      const float p2 = __expf(s[ks][2] - mn), p3 = __expf(s[ks][3] - mn);
      const float q0 = p0 * km4.x, q1 = p1 * km4.y, q2 = p2 * km4.z, q3 = p3 * km4.w;
      ps  += (p0 + p1) + (p2 + p3);
      pms += (q0 + q1) + (q2 + q3);
      uint2 pv;
      pv.x = pk2h(q0, q1);
      pv.y = pk2h(q2, q3);
      *(uint2*)&PmL[prow + ks * 16 + quad * 4] = pv;
    }
    Zp  = Zp  * alpha + ps;
    Zmp = Zmp * alpha + pms;
#pragma unroll
    for (int dt = 0; dt < 4; dt++) OT[dt] *= alpha;

    const s16x8 p0 = *(const s16x8*)&PmL[prow + quad * 8];
    const s16x8 p1 = *(const s16x8*)&PmL[prow + 32 + quad * 8];
#pragma unroll
    for (int dt = 0; dt < 4; dt++) {
      const s16x8 a0 = *(const s16x8*)&VtL[(quad * 64 + dt * 16 + col) * 8];
      const s16x8 a1 = *(const s16x8*)&VtL[((quad + 4) * 64 + dt * 16 + col) * 8];
      OT[dt] = __builtin_amdgcn_mfma_f32_16x16x32_f16(a0, p0, OT[dt], 0, 0, 0);
      OT[dt] = __builtin_amdgcn_mfma_f32_16x16x32_f16(a1, p1, OT[dt], 0, 0, 0);
    }
  }

  Zp  += __shfl_xor(Zp,  16, 64);  Zp  += __shfl_xor(Zp,  32, 64);
  Zmp += __shfl_xor(Zmp, 16, 64);  Zmp += __shfl_xor(Zmp, 32, 64);

  const int q     = qbase + col;
  const float qmv = Qm[b * Sc + q];
  const float rden = (qmv != 0.0f) ? 1.0f / (Zmp + EPS_TERM * Zp) : 0.0f;

  ushort* crow = ctx + (size_t)(b * Sc + q) * HIDc + h * DHc + quad * 4;
#pragma unroll
  for (int dt = 0; dt < 4; dt++) {
    uint2 ov;
    ov.x = pk2h(OT[dt][0] * rden, OT[dt][1] * rden);
    ov.y = pk2h(OT[dt][2] * rden, OT[dt][3] * rden);
    *(uint2*)(crow + dt * 16) = ov;
  }
}

// ---------------------------------------------------------------------------
extern "C" void kernel_launch(void* const* d_in, const int* in_sizes, int n_in,
                              void* d_out, int out_size, void* d_ws, size_t ws_size,
                              hipStream_t stream)
{
  const float* Q  = (const float*)d_in[0];
  const float* K  = (const float*)d_in[1];
  const float* V  = (const float*)d_in[2];
  const float* Qm = (const float*)d_in[3];
  const float* Km = (const float*)d_in[4];
  const float* Wq = (const float*)d_in[5];
  const float* bq = (const float*)d_in[6];
  const float* Wk = (const float*)d_in[7];
  const float* bk = (const float*)d_in[8];
  const float* Wv = (const float*)d_in[9];
  const float* bv = (const float*)d_in[10];
  const float* Wo = (const float*)d_in[11];
  const float* bo = (const float*)d_in[12];
  float* out = (float*)d_out;

  const size_t NEL = (size_t)Mc * HIDc;   // 8.39M
  const size_t WEL = (size_t)HIDc * HIDc; // 1.05M

  ushort* Wqh = (ushort*)d_ws;
  ushort* Wql = Wqh + WEL;
  ushort* Wkh = Wql + WEL;
  ushort* Wkl = Wkh + WEL;
  ushort* Wvh = Wkl + WEL;
  ushort* Woh = Wvh + WEL;
  ushort* qhi = Woh + WEL;
  ushort* qlo = qhi + NEL;
  ushort* kf  = qlo + NEL;
  ushort* vt  = kf  + NEL;
  ushort* ctx = vt  + NEL;
  // total: 6*WEL + 5*NEL ushorts ~= 96 MB

  const int n4w = (int)(WEL / 4);   // 262144 -> 1024 blocks/segment

  cvt_weights<<<4 * (n4w / 256), 256, 0, stream>>>(
      (const float4*)Wq, (const float4*)Wk, (const float4*)Wv, (const float4*)Wo,
      (ushort4*)Wqh, (ushort4*)Wql, (ushort4*)Wkh, (ushort4*)Wkl,
      (ushort4*)Wvh, (ushort4*)Woh, n4w);

  // fused QKV projections (1D grid, XCD swizzle inside)
  qkv_gemm<<<1536, 256, 0, stream>>>(Q, K, V,
      Wqh, Wql, Wkh, Wkl, Wvh, bq, bk, bv, qhi, qlo, kf, vt);

  // attention -> fp16 ctx
  attn_mfma<<<Bc * NHc * (Sc / 64), 256, 0, stream>>>(qhi, qlo, kf, vt, Qm, Km, ctx);

  // output projection (1D grid, XCD swizzle inside)
  o_gemm<<<512, 256, 0, stream>>>(ctx, Woh, bo, out);
}